// Round 13
// baseline (338.226 us; speedup 1.0000x reference)
//
#include <hip/hip_runtime.h>

#define N_NODES 50000
#define N_EDGES 800000
#define SCAN_NB ((N_NODES + 255) / 256)   // 196
#define NCHUNK 64
#define NRANGE 4
#define RNODES (N_NODES / NRANGE)         // 12500
#define CEDGES (N_EDGES / NCHUNK)         // 12500
#define GRID_CSR (NCHUNK * NRANGE)        // 256 blocks

typedef __attribute__((ext_vector_type(8))) short short8;
typedef __attribute__((ext_vector_type(4))) float f32x4;

struct LPtrs { const float *W1, *W2, *W3, *Wl, *b1, *b3, *bl; };
struct AllPtrs { LPtrs l[3]; };

__device__ inline unsigned short f2b(float f) {
    union { float f; unsigned u; } c; c.f = f;
    return (unsigned short)((c.u + 0x7FFFu + ((c.u >> 16) & 1u)) >> 16);
}
__device__ inline float b2f(unsigned short h) {
    union { unsigned u; float f; } c; c.u = ((unsigned)h) << 16;
    return c.f;
}

// Sense-reversing grid barrier. bar[0]=count, bar[1]=generation (zeroed per
// call). Correct under guaranteed co-residency: grid=256 blocks, 50KB LDS ->
// 3 blocks/CU capacity on 256 CUs (3x margin). Device-scope atomics.
__device__ inline void gridbar(int* bar) {
    __syncthreads();
    if (threadIdx.x == 0) {
        __threadfence();                       // release prior writes
        int gen = atomicAdd(&bar[1], 0);
        int old = atomicAdd(&bar[0], 1);
        if (old == GRID_CSR - 1) {
            bar[0] = 0;
            __threadfence();
            atomicAdd(&bar[1], 1);
        } else {
            while (atomicAdd(&bar[1], 0) == gen) {}
        }
        __threadfence();                       // acquire
    }
    __syncthreads();
}

// ---------------------------------------------------------------------------
// Fused CSR build + weight pack, one launch, 3 grid barriers.
// Phase 1: per-(chunk,range) LDS histograms (all 256 blocks).
// Phase 2: blocks 0..195 chunk-scan + block-scan (scanA2); blocks 196..231
//          pack Wm@Wl into B-frag bf16 + bias rows (independent work).
// Phase 3: block 0 scans the 196 block sums -> boff.
// Phase 4: fill csr via LDS cursors (all 256 blocks).
__global__ __launch_bounds__(256) void csr_pack_kernel(
    const int* __restrict__ src, const int* __restrict__ dst,
    AllPtrs ap,
    unsigned short* __restrict__ hist_part,
    int* __restrict__ off, int* __restrict__ deg,
    int* __restrict__ bsum, int* __restrict__ boff,
    int* __restrict__ csr,
    unsigned short* __restrict__ Wp, float* __restrict__ rows,
    int* __restrict__ bar)
{
    __shared__ int h[RNODES];                 // 50 KB, unioned across phases
    const int b = blockIdx.x;
    const int t = threadIdx.x;

    // ---- Phase 1: histogram ----
    {
        const int chunk = b >> 2;
        const int range = b & 3;
        const int nbase = range * RNODES;
        for (int i = t; i < RNODES; i += 256) h[i] = 0;
        __syncthreads();
        const int* dp = dst + chunk * CEDGES;
        for (int i = t; i < CEDGES; i += 256) {
            int d = dp[i] - nbase;
            if ((unsigned)d < (unsigned)RNODES) atomicAdd(&h[d], 1);
        }
        __syncthreads();
        unsigned short* out = hist_part + (long)chunk * N_NODES + nbase;
        for (int i = t; i < RNODES; i += 256) out[i] = (unsigned short)h[i];
    }
    gridbar(bar);

    // ---- Phase 2: scanA2 (blocks 0..195) | pack (blocks 196..231) ----
    if (b < SCAN_NB) {
        int* tmp = h;                         // reuse LDS
        const int node = b * 256 + t;
        int run = 0;
        if (node < N_NODES) {
            #pragma unroll
            for (int c = 0; c < NCHUNK; ++c) {
                unsigned short* p = hist_part + (long)c * N_NODES + node;
                int v = *p;
                *p = (unsigned short)run;
                run += v;
            }
            deg[node] = run;
        }
        int v = run;
        __syncthreads();                      // LDS reuse guard
        tmp[t] = v;
        __syncthreads();
        #pragma unroll
        for (int d = 1; d < 256; d <<= 1) {
            int u = (t >= d) ? tmp[t - d] : 0;
            __syncthreads();
            tmp[t] += u;
            __syncthreads();
        }
        if (node < N_NODES) off[node] = tmp[t] - v;
        if (t == 255) bsum[b] = tmp[255];
    } else if (b < SCAN_NB + 36) {
        // pack: Wml = Wm@Wl in B-frag bf16; bias rows (layer, ct) work item
        float* sW = (float*)h;                // 64x65 floats
        float* sL = (float*)h + 64 * 65;      // 64x17 floats (total 21 KB)
        const int wi = b - SCAN_NB;
        const int layer = wi / 12;
        const int ct = wi % 12;
        LPtrs L = ap.l[layer];
        const float* Wm = (ct < 4) ? L.W1 : (ct < 8) ? L.W2 : L.W3;
        const int colb = (ct & 3) * 16;
        __syncthreads();                      // LDS reuse guard
        for (int i = t; i < 64 * 64; i += 256) sW[(i >> 6) * 65 + (i & 63)] = Wm[i];
        for (int i = t; i < 64 * 16; i += 256) {
            int q = i >> 4, c = i & 15;
            sL[q * 17 + c] = L.Wl[q * 64 + colb + c];
        }
        __syncthreads();
        for (int local = t; local < 1024; local += 256) {
            int j = local & 7, lane = (local >> 3) & 63, s = local >> 9;
            int k = s * 32 + (lane >> 4) * 8 + j;
            int c = lane & 15;
            float acc = 0.f;
            #pragma unroll 8
            for (int q = 0; q < 64; ++q) acc += sW[k * 65 + q] * sL[q * 17 + c];
            Wp[layer * 12288 + ct * 1024 + local] = f2b(acc);
        }
        if (ct == 0 && t < 64) {
            int col = t;
            float r1 = 0.f, r3 = 0.f;
            for (int q = 0; q < 64; ++q) {
                float wl = L.Wl[q * 64 + col];
                r1 += L.b1[q] * wl;
                r3 += L.b3[q] * wl;
            }
            rows[layer * 128 + col] = r1;
            rows[layer * 128 + 64 + col] = r3 + L.bl[col];
        }
    }
    gridbar(bar);

    // ---- Phase 3: scanB (block 0 only) ----
    if (b == 0) {
        int* tmp = h;
        int v = (t < SCAN_NB) ? bsum[t] : 0;
        __syncthreads();
        tmp[t] = v;
        __syncthreads();
        #pragma unroll
        for (int d = 1; d < 256; d <<= 1) {
            int u = (t >= d) ? tmp[t - d] : 0;
            __syncthreads();
            tmp[t] += u;
            __syncthreads();
        }
        if (t < SCAN_NB) boff[t] = tmp[t] - v;
    }
    gridbar(bar);

    // ---- Phase 4: fill csr ----
    {
        const int chunk = b >> 2;
        const int range = b & 3;
        const int nbase = range * RNODES;
        const unsigned short* bp = hist_part + (long)chunk * N_NODES + nbase;
        const int* op = off + nbase;
        int* cur = h;
        for (int i = t; i < RNODES; i += 256)
            cur[i] = op[i] + boff[(nbase + i) >> 8] + (int)bp[i];
        __syncthreads();
        const int* dp = dst + chunk * CEDGES;
        const int* sp = src + chunk * CEDGES;
        for (int i = t; i < CEDGES; i += 256) {
            int d = dp[i] - nbase;
            if ((unsigned)d < (unsigned)RNODES) {
                int pos = atomicAdd(&cur[d], 1);
                csr[pos] = sp[i];
            }
        }
    }
}

// ---------------------------------------------------------------------------
// a' = h@W1l; w = (h@W3l) - deg*( (h@W2l) - row1 ) + row3, one pass.
// bf16 MFMA, no LDS. hf32 != null (layer 0): read fp32 x, cast in-register.
__global__ __launch_bounds__(256) void gemm3w_kernel(
    const unsigned short* __restrict__ hbf, const float* __restrict__ hf32,
    const unsigned short* __restrict__ Wp,
    const int* __restrict__ deg, const float* __restrict__ rows,
    unsigned short* __restrict__ abf, unsigned short* __restrict__ wbf, int n)
{
    const int t = threadIdx.x;
    const int lane = t & 63;
    const int quad = lane >> 4, lm = lane & 15;
    const int row_base = blockIdx.x * 64 + (t >> 6) * 16;

    int arow = min(row_base + lm, n - 1);
    short8 a0, a1;
    if (hf32) {
        const float* hrow = hf32 + (long)arow * 64;
        #pragma unroll
        for (int j = 0; j < 8; ++j) {
            a0[j] = (short)f2b(hrow[quad * 8 + j]);
            a1[j] = (short)f2b(hrow[32 + quad * 8 + j]);
        }
    } else {
        const unsigned short* hrow = hbf + (long)arow * 64;
        a0 = *(const short8*)(hrow + quad * 8);
        a1 = *(const short8*)(hrow + 32 + quad * 8);
    }

    const short8* wp = (const short8*)Wp;
    f32x4 acc[12];
    #pragma unroll
    for (int ct = 0; ct < 12; ++ct) {
        f32x4 z = {0.f, 0.f, 0.f, 0.f};
        short8 w0 = wp[(ct * 2 + 0) * 64 + lane];
        short8 w1 = wp[(ct * 2 + 1) * 64 + lane];
        z = __builtin_amdgcn_mfma_f32_16x16x32_bf16(a0, w0, z, 0, 0, 0);
        z = __builtin_amdgcn_mfma_f32_16x16x32_bf16(a1, w1, z, 0, 0, 0);
        acc[ct] = z;
    }

    const int g0 = row_base + quad * 4;
    float dg[4];
    #pragma unroll
    for (int r = 0; r < 4; ++r) dg[r] = (float)deg[min(g0 + r, n - 1)];

    #pragma unroll
    for (int ct = 0; ct < 4; ++ct) {
        int col = ct * 16 + lm;
        float r1 = rows[col];
        float r3 = rows[64 + col];
        #pragma unroll
        for (int r = 0; r < 4; ++r) {
            int g = g0 + r;
            if (g < n) {
                abf[(long)g * 64 + col] = f2b(acc[ct][r]);
                float wv = acc[8 + ct][r] - dg[r] * (acc[4 + ct][r] - r1) + r3;
                wbf[(long)g * 64 + col] = f2b(wv);
            }
        }
    }
}

// ---------------------------------------------------------------------------
// CSR gather + output: one wave per node; lane = (edge group g = lane>>3,
// feature octet f = (lane&7)*8); 1 KB per load instr; 3-round xor-shuffle
// reduce; out = relu(S' + w).
__global__ __launch_bounds__(256) void gather_out_kernel(
    const int* __restrict__ off, const int* __restrict__ boff,
    const int* __restrict__ degv, const int* __restrict__ csr,
    const unsigned short* __restrict__ abf,
    const unsigned short* __restrict__ wbf,
    float* __restrict__ out_f, unsigned short* __restrict__ out_b, int last)
{
    int node = blockIdx.x * 4 + (threadIdx.x >> 6);
    int lane = threadIdx.x & 63;
    const int g = lane >> 3;        // 0..7 edge group
    const int f = (lane & 7) * 8;   // feature octet
    int beg = off[node] + boff[node >> 8];
    int end = beg + degv[node];
    float acc[8];
    #pragma unroll
    for (int q = 0; q < 8; ++q) acc[q] = 0.f;
    int j = beg;
    for (; j + 16 <= end; j += 16) {
        int s0 = csr[j + g], s1 = csr[j + 8 + g];
        short8 v0 = *(const short8*)(abf + (long)s0 * 64 + f);
        short8 v1 = *(const short8*)(abf + (long)s1 * 64 + f);
        #pragma unroll
        for (int q = 0; q < 8; ++q)
            acc[q] += b2f((unsigned short)v0[q]) + b2f((unsigned short)v1[q]);
    }
    for (; j < end; j += 8) {
        int jj = j + g;
        if (jj < end) {
            int s0 = csr[jj];
            short8 v0 = *(const short8*)(abf + (long)s0 * 64 + f);
            #pragma unroll
            for (int q = 0; q < 8; ++q) acc[q] += b2f((unsigned short)v0[q]);
        }
    }
    #pragma unroll
    for (int m = 8; m < 64; m <<= 1) {
        #pragma unroll
        for (int q = 0; q < 8; ++q) acc[q] += __shfl_xor(acc[q], m, 64);
    }
    if (g == 0) {
        short8 wv = *(const short8*)(wbf + (long)node * 64 + f);
        float o[8];
        #pragma unroll
        for (int q = 0; q < 8; ++q)
            o[q] = fmaxf(acc[q] + b2f((unsigned short)wv[q]), 0.f);
        if (last) {
            float4 o0 = {o[0], o[1], o[2], o[3]};
            float4 o1 = {o[4], o[5], o[6], o[7]};
            *(float4*)(out_f + (long)node * 64 + f) = o0;
            *(float4*)(out_f + (long)node * 64 + f + 4) = o1;
        } else {
            short8 ob;
            #pragma unroll
            for (int q = 0; q < 8; ++q) ob[q] = (short)f2b(o[q]);
            *(short8*)(out_b + (long)node * 64 + f) = ob;
        }
    }
}

// ---------------------------------------------------------------------------
extern "C" void kernel_launch(void* const* d_in, const int* in_sizes, int n_in,
                              void* d_out, int out_size, void* d_ws, size_t ws_size,
                              hipStream_t stream) {
    const float* x  = (const float*)d_in[0];
    const int*   ei = (const int*)d_in[1];
    const int*   src = ei;
    const int*   dst = ei + N_EDGES;

    char* wsb = (char*)d_ws;
    unsigned short* hist_part = (unsigned short*)(wsb);         // 6.4 MB
    unsigned short* abf  = (unsigned short*)(wsb + 12800000);   // 6.4 MB
    unsigned short* wbf  = (unsigned short*)(wsb + 19200000);   // 6.4 MB
    unsigned short* h1   = (unsigned short*)(wsb + 25600000);   // 6.4 MB
    unsigned short* Wp   = (unsigned short*)(wsb + 38400000);   // 72 KB
    float*          rows = (float*)(wsb + 38500000);            // 1.5 KB
    int* off  = (int*)(wsb + 38600000);                         // N_NODES
    int* deg  = off + N_NODES;                                  // N_NODES
    int* bsum = deg + N_NODES;                                  // SCAN_NB
    int* boff = bsum + SCAN_NB;                                 // SCAN_NB
    int* bar  = boff + SCAN_NB;                                 // 2 ints
    int* csr  = bar + 2;                                        // N_EDGES

    const int NBLK = (N_NODES + 63) / 64;    // 782

    AllPtrs ap;
    for (int l = 0; l < 3; ++l) {
        int base = 2 + l * 7;
        ap.l[l].W1 = (const float*)d_in[base + 0];
        ap.l[l].b1 = (const float*)d_in[base + 1];
        ap.l[l].W2 = (const float*)d_in[base + 2];
        ap.l[l].W3 = (const float*)d_in[base + 3];
        ap.l[l].b3 = (const float*)d_in[base + 4];
        ap.l[l].Wl = (const float*)d_in[base + 5];
        ap.l[l].bl = (const float*)d_in[base + 6];
    }

    // ---- fused CSR build + weight pack: 1 launch (+8-byte barrier init) ----
    hipMemsetAsync(bar, 0, 2 * sizeof(int), stream);
    csr_pack_kernel<<<GRID_CSR, 256, 0, stream>>>(
        src, dst, ap, hist_part, off, deg, bsum, boff, csr, Wp, rows, bar);

    const unsigned short* hin = nullptr;   // layer 0 reads x directly
    for (int l = 0; l < 3; ++l) {
        const unsigned short* wp = Wp + l * 12288;
        gemm3w_kernel<<<NBLK, 256, 0, stream>>>(
            hin, (l == 0) ? x : nullptr, wp, deg, rows + l * 128,
            abf, wbf, N_NODES);

        int last = (l == 2);
        gather_out_kernel<<<N_NODES / 4, 256, 0, stream>>>(
            off, boff, deg, csr, abf, wbf, (float*)d_out, h1, last);
        hin = h1;
    }
}

// Round 14
// 271.675 us; speedup vs baseline: 1.2450x; 1.2450x over previous
//
#include <hip/hip_runtime.h>

#define N_NODES 50000
#define N_EDGES 800000
#define SCAN_NB ((N_NODES + 255) / 256)   // 196
#define NCHUNK 128
#define NRANGE 4
#define RNODES (N_NODES / NRANGE)         // 12500
#define CEDGES (N_EDGES / NCHUNK)         // 6250

typedef __attribute__((ext_vector_type(8))) short short8;
typedef __attribute__((ext_vector_type(4))) float f32x4;

struct LPtrs { const float *W1, *W2, *W3, *Wl, *b1, *b3, *bl; };
struct AllPtrs { LPtrs l[3]; };

__device__ inline unsigned short f2b(float f) {
    union { float f; unsigned u; } c; c.f = f;
    return (unsigned short)((c.u + 0x7FFFu + ((c.u >> 16) & 1u)) >> 16);
}
__device__ inline float b2f(unsigned short h) {
    union { unsigned u; float f; } c; c.u = ((unsigned)h) << 16;
    return c.f;
}

// ---------------------------------------------------------------------------
// K1: partial histograms (u16). Block = (chunk, range). LDS atomics only.
__global__ __launch_bounds__(256) void histp_kernel(const int* __restrict__ dst,
                                                    unsigned short* __restrict__ hist_part) {
    __shared__ int h[RNODES];
    const int chunk = blockIdx.x >> 2;
    const int range = blockIdx.x & 3;
    const int nbase = range * RNODES;
    for (int i = threadIdx.x; i < RNODES; i += 256) h[i] = 0;
    __syncthreads();
    const int* dp = dst + chunk * CEDGES;
    for (int i = threadIdx.x; i < CEDGES; i += 256) {
        int d = dp[i] - nbase;
        if ((unsigned)d < (unsigned)RNODES) atomicAdd(&h[d], 1);
    }
    __syncthreads();
    unsigned short* out = hist_part + (long)chunk * N_NODES + nbase;
    for (int i = threadIdx.x; i < RNODES; i += 256) out[i] = (unsigned short)h[i];
}

// ---------------------------------------------------------------------------
// K2 (fused chunkscan + scanA): per node, exclusive scan across chunks
// (in place, u16) -> per-chunk bases; node total -> deg[]; block-scan the
// totals -> partial off[] + per-block sums bsum[].
__global__ __launch_bounds__(256) void scanA2_kernel(unsigned short* __restrict__ hist_part,
                                                     int* __restrict__ off,
                                                     int* __restrict__ deg,
                                                     int* __restrict__ bsum) {
    __shared__ int tmp[256];
    const int t = threadIdx.x;
    const int node = blockIdx.x * 256 + t;
    int run = 0;
    if (node < N_NODES) {
        #pragma unroll
        for (int c = 0; c < NCHUNK; ++c) {
            unsigned short* p = hist_part + (long)c * N_NODES + node;
            int v = *p;
            *p = (unsigned short)run;
            run += v;
        }
        deg[node] = run;
    }
    int v = run;
    tmp[t] = v;
    __syncthreads();
    #pragma unroll
    for (int d = 1; d < 256; d <<= 1) {
        int u = (t >= d) ? tmp[t - d] : 0;
        __syncthreads();
        tmp[t] += u;
        __syncthreads();
    }
    if (node < N_NODES) off[node] = tmp[t] - v;   // partial (needs boff)
    if (t == 255) bsum[blockIdx.x] = tmp[255];
}

// ---------------------------------------------------------------------------
// K3: fill csr; scanB folded in. Every block redundantly scans the 196
// block sums in LDS (parallel, ~1 us); block 0 publishes boff for
// gather_out. Cursor = off[d] + boff[node>>8] + base[chunk][d] in LDS;
// LDS atomics rank edges; plain global stores only (L2-absorbed).
__global__ __launch_bounds__(256) void fillp_kernel(const int* __restrict__ src,
                                                    const int* __restrict__ dst,
                                                    const int* __restrict__ off,
                                                    const int* __restrict__ bsum,
                                                    int* __restrict__ boff,
                                                    const unsigned short* __restrict__ hist_part,
                                                    int* __restrict__ csr) {
    __shared__ int cur[RNODES];
    __shared__ int sb[256];
    const int t = threadIdx.x;
    // redundant per-block scan of bsum -> sb[] holds exclusive prefix
    int v = (t < SCAN_NB) ? bsum[t] : 0;
    sb[t] = v;
    __syncthreads();
    #pragma unroll
    for (int d = 1; d < 256; d <<= 1) {
        int u = (t >= d) ? sb[t - d] : 0;
        __syncthreads();
        sb[t] += u;
        __syncthreads();
    }
    int excl = sb[t] - v;
    __syncthreads();
    sb[t] = excl;
    if (blockIdx.x == 0 && t < SCAN_NB) boff[t] = excl;
    __syncthreads();

    const int chunk = blockIdx.x >> 2;
    const int range = blockIdx.x & 3;
    const int nbase = range * RNODES;
    const unsigned short* bp = hist_part + (long)chunk * N_NODES + nbase;
    const int* op = off + nbase;
    for (int i = t; i < RNODES; i += 256)
        cur[i] = op[i] + sb[(nbase + i) >> 8] + (int)bp[i];
    __syncthreads();
    const int* dp = dst + chunk * CEDGES;
    const int* sp = src + chunk * CEDGES;
    for (int i = t; i < CEDGES; i += 256) {
        int d = dp[i] - nbase;
        if ((unsigned)d < (unsigned)RNODES) {
            int pos = atomicAdd(&cur[d], 1);
            csr[pos] = sp[i];
        }
    }
}

// ---------------------------------------------------------------------------
// Precompute: Wml = Wm @ Wl (m=1,2,3) packed into B-fragment bf16 layout,
// plus row1 = b1@Wl and row3 = b3@Wl + bl per layer.
// Grid = 3 layers x 12 col-tiles.
__global__ __launch_bounds__(256) void pack_mm_kernel(AllPtrs ap,
                                                      unsigned short* __restrict__ Wp,
                                                      float* __restrict__ rows)
{
    __shared__ float sW[64][65];   // Wm, padded
    __shared__ float sL[64][17];   // Wl[:, colb..colb+15], padded
    const int layer = blockIdx.x / 12;
    const int ct = blockIdx.x % 12;
    LPtrs L = ap.l[layer];
    const float* Wm = (ct < 4) ? L.W1 : (ct < 8) ? L.W2 : L.W3;
    const int colb = (ct & 3) * 16;

    for (int i = threadIdx.x; i < 64 * 64; i += 256) sW[i >> 6][i & 63] = Wm[i];
    for (int i = threadIdx.x; i < 64 * 16; i += 256) {
        int q = i >> 4, c = i & 15;
        sL[q][c] = L.Wl[q * 64 + colb + c];
    }
    __syncthreads();

    for (int local = threadIdx.x; local < 1024; local += 256) {
        int j = local & 7, lane = (local >> 3) & 63, s = local >> 9;
        int k = s * 32 + (lane >> 4) * 8 + j;
        int c = lane & 15;
        float acc = 0.f;
        #pragma unroll 8
        for (int q = 0; q < 64; ++q) acc += sW[k][q] * sL[q][c];
        Wp[layer * 12288 + ct * 1024 + local] = f2b(acc);
    }

    if (ct == 0 && threadIdx.x < 64) {
        int col = threadIdx.x;
        float r1 = 0.f, r3 = 0.f;
        for (int q = 0; q < 64; ++q) {
            float wl = L.Wl[q * 64 + col];
            r1 += L.b1[q] * wl;
            r3 += L.b3[q] * wl;
        }
        rows[layer * 128 + col] = r1;
        rows[layer * 128 + 64 + col] = r3 + L.bl[col];
    }
}

// ---------------------------------------------------------------------------
// a' = h@W1l; w = (h@W3l) - deg*( (h@W2l) - row1 ) + row3, one pass.
// bf16 MFMA, no LDS. hf32 != null (layer 0): read fp32 x, cast in-register.
__global__ __launch_bounds__(256) void gemm3w_kernel(
    const unsigned short* __restrict__ hbf, const float* __restrict__ hf32,
    const unsigned short* __restrict__ Wp,
    const int* __restrict__ deg, const float* __restrict__ rows,
    unsigned short* __restrict__ abf, unsigned short* __restrict__ wbf, int n)
{
    const int t = threadIdx.x;
    const int lane = t & 63;
    const int quad = lane >> 4, lm = lane & 15;
    const int row_base = blockIdx.x * 64 + (t >> 6) * 16;

    int arow = min(row_base + lm, n - 1);
    short8 a0, a1;
    if (hf32) {
        const float* hrow = hf32 + (long)arow * 64;
        #pragma unroll
        for (int j = 0; j < 8; ++j) {
            a0[j] = (short)f2b(hrow[quad * 8 + j]);
            a1[j] = (short)f2b(hrow[32 + quad * 8 + j]);
        }
    } else {
        const unsigned short* hrow = hbf + (long)arow * 64;
        a0 = *(const short8*)(hrow + quad * 8);
        a1 = *(const short8*)(hrow + 32 + quad * 8);
    }

    const short8* wp = (const short8*)Wp;
    f32x4 acc[12];
    #pragma unroll
    for (int ct = 0; ct < 12; ++ct) {
        f32x4 z = {0.f, 0.f, 0.f, 0.f};
        short8 w0 = wp[(ct * 2 + 0) * 64 + lane];
        short8 w1 = wp[(ct * 2 + 1) * 64 + lane];
        z = __builtin_amdgcn_mfma_f32_16x16x32_bf16(a0, w0, z, 0, 0, 0);
        z = __builtin_amdgcn_mfma_f32_16x16x32_bf16(a1, w1, z, 0, 0, 0);
        acc[ct] = z;
    }

    const int g0 = row_base + quad * 4;
    float dg[4];
    #pragma unroll
    for (int r = 0; r < 4; ++r) dg[r] = (float)deg[min(g0 + r, n - 1)];

    #pragma unroll
    for (int ct = 0; ct < 4; ++ct) {
        int col = ct * 16 + lm;
        float r1 = rows[col];
        float r3 = rows[64 + col];
        #pragma unroll
        for (int r = 0; r < 4; ++r) {
            int g = g0 + r;
            if (g < n) {
                abf[(long)g * 64 + col] = f2b(acc[ct][r]);
                float wv = acc[8 + ct][r] - dg[r] * (acc[4 + ct][r] - r1) + r3;
                wbf[(long)g * 64 + col] = f2b(wv);
            }
        }
    }
}

// ---------------------------------------------------------------------------
// CSR gather + output: one wave per node; lane = (edge group g, feature
// quad f); 512 B per load instr; xor-shuffle reduce; out = relu(S' + w).
__global__ __launch_bounds__(256) void gather_out_kernel(
    const int* __restrict__ off, const int* __restrict__ boff,
    const int* __restrict__ degv, const int* __restrict__ csr,
    const unsigned short* __restrict__ abf,
    const unsigned short* __restrict__ wbf,
    float* __restrict__ out_f, unsigned short* __restrict__ out_b, int last)
{
    int node = blockIdx.x * 4 + (threadIdx.x >> 6);
    int lane = threadIdx.x & 63;
    const int g = lane >> 4;
    const int f = (lane & 15) * 4;
    int beg = off[node] + boff[node >> 8];
    int end = beg + degv[node];
    float ax = 0.f, ay = 0.f, az = 0.f, aw = 0.f;
    int j = beg;
    for (; j + 8 <= end; j += 8) {
        int s0 = csr[j + g], s1 = csr[j + 4 + g];
        ushort4 v0 = *(const ushort4*)(abf + (long)s0 * 64 + f);
        ushort4 v1 = *(const ushort4*)(abf + (long)s1 * 64 + f);
        ax += b2f(v0.x) + b2f(v1.x);
        ay += b2f(v0.y) + b2f(v1.y);
        az += b2f(v0.z) + b2f(v1.z);
        aw += b2f(v0.w) + b2f(v1.w);
    }
    for (; j < end; j += 4) {
        int jj = j + g;
        if (jj < end) {
            int s0 = csr[jj];
            ushort4 v0 = *(const ushort4*)(abf + (long)s0 * 64 + f);
            ax += b2f(v0.x); ay += b2f(v0.y); az += b2f(v0.z); aw += b2f(v0.w);
        }
    }
    #pragma unroll
    for (int m = 16; m < 64; m <<= 1) {
        ax += __shfl_xor(ax, m, 64);
        ay += __shfl_xor(ay, m, 64);
        az += __shfl_xor(az, m, 64);
        aw += __shfl_xor(aw, m, 64);
    }
    if (g == 0) {
        ushort4 wv = *(const ushort4*)(wbf + (long)node * 64 + f);
        float o0 = fmaxf(ax + b2f(wv.x), 0.f);
        float o1 = fmaxf(ay + b2f(wv.y), 0.f);
        float o2 = fmaxf(az + b2f(wv.z), 0.f);
        float o3 = fmaxf(aw + b2f(wv.w), 0.f);
        if (last) {
            float4 o = {o0, o1, o2, o3};
            *(float4*)(out_f + (long)node * 64 + f) = o;
        } else {
            ushort4 o;
            o.x = f2b(o0); o.y = f2b(o1); o.z = f2b(o2); o.w = f2b(o3);
            *(ushort4*)(out_b + (long)node * 64 + f) = o;
        }
    }
}

// ---------------------------------------------------------------------------
extern "C" void kernel_launch(void* const* d_in, const int* in_sizes, int n_in,
                              void* d_out, int out_size, void* d_ws, size_t ws_size,
                              hipStream_t stream) {
    const float* x  = (const float*)d_in[0];
    const int*   ei = (const int*)d_in[1];
    const int*   src = ei;
    const int*   dst = ei + N_EDGES;

    char* wsb = (char*)d_ws;
    unsigned short* hist_part = (unsigned short*)(wsb);         // 12.8 MB
    unsigned short* abf  = (unsigned short*)(wsb + 12800000);   // 6.4 MB
    unsigned short* wbf  = (unsigned short*)(wsb + 19200000);   // 6.4 MB
    unsigned short* h1   = (unsigned short*)(wsb + 25600000);   // 6.4 MB
    unsigned short* Wp   = (unsigned short*)(wsb + 38400000);   // 72 KB
    float*          rows = (float*)(wsb + 38500000);            // 1.5 KB
    int* off  = (int*)(wsb + 38600000);                         // N_NODES
    int* deg  = off + N_NODES;                                  // N_NODES
    int* bsum = deg + N_NODES;                                  // SCAN_NB
    int* boff = bsum + SCAN_NB;                                 // SCAN_NB
    int* csr  = boff + SCAN_NB;                                 // N_EDGES

    const int NBLK = (N_NODES + 63) / 64;    // 782

    // ---- CSR build: zero global atomics, 3 launches ----
    histp_kernel<<<NCHUNK * NRANGE, 256, 0, stream>>>(dst, hist_part);
    scanA2_kernel<<<SCAN_NB, 256, 0, stream>>>(hist_part, off, deg, bsum);
    fillp_kernel<<<NCHUNK * NRANGE, 256, 0, stream>>>(src, dst, off, bsum, boff,
                                                      hist_part, csr);

    // ---- weight-product packing (W1@Wl, W2@Wl, W3@Wl + bias rows) ----
    AllPtrs ap;
    for (int l = 0; l < 3; ++l) {
        int base = 2 + l * 7;
        ap.l[l].W1 = (const float*)d_in[base + 0];
        ap.l[l].b1 = (const float*)d_in[base + 1];
        ap.l[l].W2 = (const float*)d_in[base + 2];
        ap.l[l].W3 = (const float*)d_in[base + 3];
        ap.l[l].b3 = (const float*)d_in[base + 4];
        ap.l[l].Wl = (const float*)d_in[base + 5];
        ap.l[l].bl = (const float*)d_in[base + 6];
    }
    pack_mm_kernel<<<36, 256, 0, stream>>>(ap, Wp, rows);

    const unsigned short* hin = nullptr;   // layer 0 reads x directly
    for (int l = 0; l < 3; ++l) {
        const unsigned short* wp = Wp + l * 12288;
        gemm3w_kernel<<<NBLK, 256, 0, stream>>>(
            hin, (l == 0) ? x : nullptr, wp, deg, rows + l * 128,
            abf, wbf, N_NODES);

        int last = (l == 2);
        gather_out_kernel<<<N_NODES / 4, 256, 0, stream>>>(
            off, boff, deg, csr, abf, wbf, (float*)d_out, h1, last);
        hin = h1;
    }
}

// Round 15
// 260.032 us; speedup vs baseline: 1.3007x; 1.0448x over previous
//
#include <hip/hip_runtime.h>

#define N_NODES 50000
#define N_EDGES 800000
#define SCAN_NB ((N_NODES + 255) / 256)   // 196
#define NCHUNK 128
#define NRANGE 4
#define RNODES (N_NODES / NRANGE)         // 12500
#define CEDGES (N_EDGES / NCHUNK)         // 6250
#define HIST_NB (NCHUNK * NRANGE)         // 512

typedef __attribute__((ext_vector_type(8))) short short8;
typedef __attribute__((ext_vector_type(4))) float f32x4;

struct LPtrs { const float *W1, *W2, *W3, *Wl, *b1, *b3, *bl; };
struct AllPtrs { LPtrs l[3]; };

__device__ inline unsigned short f2b(float f) {
    union { float f; unsigned u; } c; c.f = f;
    return (unsigned short)((c.u + 0x7FFFu + ((c.u >> 16) & 1u)) >> 16);
}
__device__ inline float b2f(unsigned short h) {
    union { unsigned u; float f; } c; c.u = ((unsigned)h) << 16;
    return c.f;
}

// ---------------------------------------------------------------------------
// K1 (fused): blocks 0..511 build partial histograms (u8, LDS atomics only);
// blocks 512..547 pack Wml = Wm@Wl into B-frag bf16 + bias rows (independent).
__global__ __launch_bounds__(256) void histpack_kernel(const int* __restrict__ dst,
                                                       unsigned char* __restrict__ hist_part,
                                                       AllPtrs ap,
                                                       unsigned short* __restrict__ Wp,
                                                       float* __restrict__ rows) {
    __shared__ int h[RNODES];                 // 50 KB (pack path reuses 21 KB)
    const int t = threadIdx.x;
    if (blockIdx.x < HIST_NB) {
        const int chunk = blockIdx.x >> 2;
        const int range = blockIdx.x & 3;
        const int nbase = range * RNODES;
        for (int i = t; i < RNODES; i += 256) h[i] = 0;
        __syncthreads();
        const int* dp = dst + chunk * CEDGES;
        for (int i = t; i < CEDGES; i += 256) {
            int d = dp[i] - nbase;
            if ((unsigned)d < (unsigned)RNODES) atomicAdd(&h[d], 1);
        }
        __syncthreads();
        unsigned char* out = hist_part + (long)chunk * N_NODES + nbase;
        for (int i = t; i < RNODES; i += 256) out[i] = (unsigned char)h[i];
    } else {
        float* sW = (float*)h;                // 64x65
        float* sL = (float*)h + 64 * 65;      // 64x17 (21 KB total)
        const int wi = blockIdx.x - HIST_NB;
        const int layer = wi / 12;
        const int ct = wi % 12;
        LPtrs L = ap.l[layer];
        const float* Wm = (ct < 4) ? L.W1 : (ct < 8) ? L.W2 : L.W3;
        const int colb = (ct & 3) * 16;
        for (int i = t; i < 64 * 64; i += 256) sW[(i >> 6) * 65 + (i & 63)] = Wm[i];
        for (int i = t; i < 64 * 16; i += 256) {
            int q = i >> 4, c = i & 15;
            sL[q * 17 + c] = L.Wl[q * 64 + colb + c];
        }
        __syncthreads();
        for (int local = t; local < 1024; local += 256) {
            int j = local & 7, lane = (local >> 3) & 63, s = local >> 9;
            int k = s * 32 + (lane >> 4) * 8 + j;
            int c = lane & 15;
            float acc = 0.f;
            #pragma unroll 8
            for (int q = 0; q < 64; ++q) acc += sW[k * 65 + q] * sL[q * 17 + c];
            Wp[layer * 12288 + ct * 1024 + local] = f2b(acc);
        }
        if (ct == 0 && t < 64) {
            int col = t;
            float r1 = 0.f, r3 = 0.f;
            for (int q = 0; q < 64; ++q) {
                float wl = L.Wl[q * 64 + col];
                r1 += L.b1[q] * wl;
                r3 += L.b3[q] * wl;
            }
            rows[layer * 128 + col] = r1;
            rows[layer * 128 + 64 + col] = r3 + L.bl[col];
        }
    }
}

// ---------------------------------------------------------------------------
// K2: per node, exclusive scan across chunks (in place, u8; prefix <= deg
// <= ~45 for this graph) -> per-chunk bases; node total -> deg[]; block-scan
// totals -> partial off[] + per-block sums bsum[].
__global__ __launch_bounds__(256) void scanA2_kernel(unsigned char* __restrict__ hist_part,
                                                     int* __restrict__ off,
                                                     int* __restrict__ deg,
                                                     int* __restrict__ bsum) {
    __shared__ int tmp[256];
    const int t = threadIdx.x;
    const int node = blockIdx.x * 256 + t;
    int run = 0;
    if (node < N_NODES) {
        #pragma unroll
        for (int c = 0; c < NCHUNK; ++c) {
            unsigned char* p = hist_part + (long)c * N_NODES + node;
            int v = *p;
            *p = (unsigned char)run;
            run += v;
        }
        deg[node] = run;
    }
    int v = run;
    tmp[t] = v;
    __syncthreads();
    #pragma unroll
    for (int d = 1; d < 256; d <<= 1) {
        int u = (t >= d) ? tmp[t - d] : 0;
        __syncthreads();
        tmp[t] += u;
        __syncthreads();
    }
    if (node < N_NODES) off[node] = tmp[t] - v;   // partial (needs boff)
    if (t == 255) bsum[blockIdx.x] = tmp[255];
}

// ---------------------------------------------------------------------------
// K3: fill csr; scanB folded in (each block redundantly scans the 196 block
// sums in LDS; block 0 publishes boff). Cursor = off + boff + chunk base in
// LDS; LDS atomics rank edges; plain global stores only.
__global__ __launch_bounds__(256) void fillp_kernel(const int* __restrict__ src,
                                                    const int* __restrict__ dst,
                                                    const int* __restrict__ off,
                                                    const int* __restrict__ bsum,
                                                    int* __restrict__ boff,
                                                    const unsigned char* __restrict__ hist_part,
                                                    int* __restrict__ csr) {
    __shared__ int cur[RNODES];
    __shared__ int sb[256];
    const int t = threadIdx.x;
    int v = (t < SCAN_NB) ? bsum[t] : 0;
    sb[t] = v;
    __syncthreads();
    #pragma unroll
    for (int d = 1; d < 256; d <<= 1) {
        int u = (t >= d) ? sb[t - d] : 0;
        __syncthreads();
        sb[t] += u;
        __syncthreads();
    }
    int excl = sb[t] - v;
    __syncthreads();
    sb[t] = excl;
    if (blockIdx.x == 0 && t < SCAN_NB) boff[t] = excl;
    __syncthreads();

    const int chunk = blockIdx.x >> 2;
    const int range = blockIdx.x & 3;
    const int nbase = range * RNODES;
    const unsigned char* bp = hist_part + (long)chunk * N_NODES + nbase;
    const int* op = off + nbase;
    for (int i = t; i < RNODES; i += 256)
        cur[i] = op[i] + sb[(nbase + i) >> 8] + (int)bp[i];
    __syncthreads();
    const int* dp = dst + chunk * CEDGES;
    const int* sp = src + chunk * CEDGES;
    for (int i = t; i < CEDGES; i += 256) {
        int d = dp[i] - nbase;
        if ((unsigned)d < (unsigned)RNODES) {
            int pos = atomicAdd(&cur[d], 1);
            csr[pos] = sp[i];
        }
    }
}

// ---------------------------------------------------------------------------
// a' = h@W1l; w = (h@W3l) - deg*( (h@W2l) - row1 ) + row3, one pass.
// bf16 MFMA, no LDS. hf32 != null (layer 0): read fp32 x, cast in-register.
__global__ __launch_bounds__(256) void gemm3w_kernel(
    const unsigned short* __restrict__ hbf, const float* __restrict__ hf32,
    const unsigned short* __restrict__ Wp,
    const int* __restrict__ deg, const float* __restrict__ rows,
    unsigned short* __restrict__ abf, unsigned short* __restrict__ wbf, int n)
{
    const int t = threadIdx.x;
    const int lane = t & 63;
    const int quad = lane >> 4, lm = lane & 15;
    const int row_base = blockIdx.x * 64 + (t >> 6) * 16;

    int arow = min(row_base + lm, n - 1);
    short8 a0, a1;
    if (hf32) {
        const float* hrow = hf32 + (long)arow * 64;
        #pragma unroll
        for (int j = 0; j < 8; ++j) {
            a0[j] = (short)f2b(hrow[quad * 8 + j]);
            a1[j] = (short)f2b(hrow[32 + quad * 8 + j]);
        }
    } else {
        const unsigned short* hrow = hbf + (long)arow * 64;
        a0 = *(const short8*)(hrow + quad * 8);
        a1 = *(const short8*)(hrow + 32 + quad * 8);
    }

    const short8* wp = (const short8*)Wp;
    f32x4 acc[12];
    #pragma unroll
    for (int ct = 0; ct < 12; ++ct) {
        f32x4 z = {0.f, 0.f, 0.f, 0.f};
        short8 w0 = wp[(ct * 2 + 0) * 64 + lane];
        short8 w1 = wp[(ct * 2 + 1) * 64 + lane];
        z = __builtin_amdgcn_mfma_f32_16x16x32_bf16(a0, w0, z, 0, 0, 0);
        z = __builtin_amdgcn_mfma_f32_16x16x32_bf16(a1, w1, z, 0, 0, 0);
        acc[ct] = z;
    }

    const int g0 = row_base + quad * 4;
    float dg[4];
    #pragma unroll
    for (int r = 0; r < 4; ++r) dg[r] = (float)deg[min(g0 + r, n - 1)];

    #pragma unroll
    for (int ct = 0; ct < 4; ++ct) {
        int col = ct * 16 + lm;
        float r1 = rows[col];
        float r3 = rows[64 + col];
        #pragma unroll
        for (int r = 0; r < 4; ++r) {
            int g = g0 + r;
            if (g < n) {
                abf[(long)g * 64 + col] = f2b(acc[ct][r]);
                float wv = acc[8 + ct][r] - dg[r] * (acc[4 + ct][r] - r1) + r3;
                wbf[(long)g * 64 + col] = f2b(wv);
            }
        }
    }
}

// ---------------------------------------------------------------------------
// CSR gather + output: one wave per node; lane = (edge group g, feature
// quad f); 512 B per load instr; 16-edge main iteration = 4 independent
// load pairs in flight; xor-shuffle reduce; out = relu(S' + w).
__global__ __launch_bounds__(256) void gather_out_kernel(
    const int* __restrict__ off, const int* __restrict__ boff,
    const int* __restrict__ degv, const int* __restrict__ csr,
    const unsigned short* __restrict__ abf,
    const unsigned short* __restrict__ wbf,
    float* __restrict__ out_f, unsigned short* __restrict__ out_b, int last)
{
    int node = blockIdx.x * 4 + (threadIdx.x >> 6);
    int lane = threadIdx.x & 63;
    const int g = lane >> 4;
    const int f = (lane & 15) * 4;
    int beg = off[node] + boff[node >> 8];
    int end = beg + degv[node];
    float ax = 0.f, ay = 0.f, az = 0.f, aw = 0.f;
    int j = beg;
    for (; j + 16 <= end; j += 16) {
        int s0 = csr[j + g], s1 = csr[j + 4 + g];
        int s2 = csr[j + 8 + g], s3 = csr[j + 12 + g];
        ushort4 v0 = *(const ushort4*)(abf + (long)s0 * 64 + f);
        ushort4 v1 = *(const ushort4*)(abf + (long)s1 * 64 + f);
        ushort4 v2 = *(const ushort4*)(abf + (long)s2 * 64 + f);
        ushort4 v3 = *(const ushort4*)(abf + (long)s3 * 64 + f);
        ax += b2f(v0.x) + b2f(v1.x) + b2f(v2.x) + b2f(v3.x);
        ay += b2f(v0.y) + b2f(v1.y) + b2f(v2.y) + b2f(v3.y);
        az += b2f(v0.z) + b2f(v1.z) + b2f(v2.z) + b2f(v3.z);
        aw += b2f(v0.w) + b2f(v1.w) + b2f(v2.w) + b2f(v3.w);
    }
    for (; j + 8 <= end; j += 8) {
        int s0 = csr[j + g], s1 = csr[j + 4 + g];
        ushort4 v0 = *(const ushort4*)(abf + (long)s0 * 64 + f);
        ushort4 v1 = *(const ushort4*)(abf + (long)s1 * 64 + f);
        ax += b2f(v0.x) + b2f(v1.x);
        ay += b2f(v0.y) + b2f(v1.y);
        az += b2f(v0.z) + b2f(v1.z);
        aw += b2f(v0.w) + b2f(v1.w);
    }
    for (; j < end; j += 4) {
        int jj = j + g;
        if (jj < end) {
            int s0 = csr[jj];
            ushort4 v0 = *(const ushort4*)(abf + (long)s0 * 64 + f);
            ax += b2f(v0.x); ay += b2f(v0.y); az += b2f(v0.z); aw += b2f(v0.w);
        }
    }
    #pragma unroll
    for (int m = 16; m < 64; m <<= 1) {
        ax += __shfl_xor(ax, m, 64);
        ay += __shfl_xor(ay, m, 64);
        az += __shfl_xor(az, m, 64);
        aw += __shfl_xor(aw, m, 64);
    }
    if (g == 0) {
        ushort4 wv = *(const ushort4*)(wbf + (long)node * 64 + f);
        float o0 = fmaxf(ax + b2f(wv.x), 0.f);
        float o1 = fmaxf(ay + b2f(wv.y), 0.f);
        float o2 = fmaxf(az + b2f(wv.z), 0.f);
        float o3 = fmaxf(aw + b2f(wv.w), 0.f);
        if (last) {
            float4 o = {o0, o1, o2, o3};
            *(float4*)(out_f + (long)node * 64 + f) = o;
        } else {
            ushort4 o;
            o.x = f2b(o0); o.y = f2b(o1); o.z = f2b(o2); o.w = f2b(o3);
            *(ushort4*)(out_b + (long)node * 64 + f) = o;
        }
    }
}

// ---------------------------------------------------------------------------
extern "C" void kernel_launch(void* const* d_in, const int* in_sizes, int n_in,
                              void* d_out, int out_size, void* d_ws, size_t ws_size,
                              hipStream_t stream) {
    const float* x  = (const float*)d_in[0];
    const int*   ei = (const int*)d_in[1];
    const int*   src = ei;
    const int*   dst = ei + N_EDGES;

    char* wsb = (char*)d_ws;
    unsigned char*  hist_part = (unsigned char*)(wsb);          // 6.4 MB (u8)
    unsigned short* abf  = (unsigned short*)(wsb + 12800000);   // 6.4 MB
    unsigned short* wbf  = (unsigned short*)(wsb + 19200000);   // 6.4 MB
    unsigned short* h1   = (unsigned short*)(wsb + 25600000);   // 6.4 MB
    unsigned short* Wp   = (unsigned short*)(wsb + 38400000);   // 72 KB
    float*          rows = (float*)(wsb + 38500000);            // 1.5 KB
    int* off  = (int*)(wsb + 38600000);                         // N_NODES
    int* deg  = off + N_NODES;                                  // N_NODES
    int* bsum = deg + N_NODES;                                  // SCAN_NB
    int* boff = bsum + SCAN_NB;                                 // SCAN_NB
    int* csr  = boff + SCAN_NB;                                 // N_EDGES

    const int NBLK = (N_NODES + 63) / 64;    // 782

    AllPtrs ap;
    for (int l = 0; l < 3; ++l) {
        int base = 2 + l * 7;
        ap.l[l].W1 = (const float*)d_in[base + 0];
        ap.l[l].b1 = (const float*)d_in[base + 1];
        ap.l[l].W2 = (const float*)d_in[base + 2];
        ap.l[l].W3 = (const float*)d_in[base + 3];
        ap.l[l].b3 = (const float*)d_in[base + 4];
        ap.l[l].Wl = (const float*)d_in[base + 5];
        ap.l[l].bl = (const float*)d_in[base + 6];
    }

    // ---- CSR build + weight pack: 3 launches, zero global atomics ----
    histpack_kernel<<<HIST_NB + 36, 256, 0, stream>>>(dst, hist_part, ap, Wp, rows);
    scanA2_kernel<<<SCAN_NB, 256, 0, stream>>>(hist_part, off, deg, bsum);
    fillp_kernel<<<HIST_NB, 256, 0, stream>>>(src, dst, off, bsum, boff,
                                              hist_part, csr);

    const unsigned short* hin = nullptr;   // layer 0 reads x directly
    for (int l = 0; l < 3; ++l) {
        const unsigned short* wp = Wp + l * 12288;
        gemm3w_kernel<<<NBLK, 256, 0, stream>>>(
            hin, (l == 0) ? x : nullptr, wp, deg, rows + l * 128,
            abf, wbf, N_NODES);

        int last = (l == 2);
        gather_out_kernel<<<N_NODES / 4, 256, 0, stream>>>(
            off, boff, deg, csr, abf, wbf, (float*)d_out, h1, last);
        hin = h1;
    }
}